// Round 1
// baseline (80.353 us; speedup 1.0000x reference)
//
#include <hip/hip_runtime.h>
#include <cstddef>

#define Bn 16
#define Dn 512
#define Tn 2048
#define Ln 512

__constant__ float kSigmaSq = 5.0f;

// ---------------- K1: score[b,t] = exp(x[b,:,t].w) * mask ----------------
__global__ __launch_bounds__(256) void score_kernel(const float* __restrict__ x,
                                                    const float* __restrict__ w,
                                                    const int* __restrict__ xlen,
                                                    float* __restrict__ score) {
    int blk  = blockIdx.x;          // B * (T/64) = 512 blocks
    int b    = blk >> 5;
    int tc   = blk & 31;
    int lane = threadIdx.x & 63;
    int dg   = threadIdx.x >> 6;    // 4 d-groups of 128
    int t    = tc * 64 + lane;
    const float* xb = x + (size_t)b * Dn * Tn;
    float acc = 0.f;
    int d0 = dg * 128;
#pragma unroll 8
    for (int d = d0; d < d0 + 128; ++d)
        acc = fmaf(xb[(size_t)d * Tn + t], w[d], acc);
    __shared__ float red[4][64];
    red[dg][lane] = acc;
    __syncthreads();
    if (dg == 0) {
        float s = red[0][lane] + red[1][lane] + red[2][lane] + red[3][lane];
        score[b * Tn + t] = (t < xlen[b]) ? __expf(s) : 0.f;
    }
}

// ---------------- K2: per-b scan -> norm, loss partial, z_mask, z_len ----
__global__ __launch_bounds__(256) void scan_kernel(const float* __restrict__ score,
                                                   const int* __restrict__ xlen,
                                                   float* __restrict__ norm,
                                                   float* __restrict__ loss_part,
                                                   float* __restrict__ zmask_out,
                                                   float* __restrict__ zlen_out) {
    int b = blockIdx.x, tid = threadIdx.x;
    int xl = xlen[b];
    int zl = (xl + 3) >> 2;
    const float* sc = score + b * Tn;

    float v[8]; float s = 0.f;
#pragma unroll
    for (int k = 0; k < 8; ++k) { v[k] = sc[tid * 8 + k]; s += v[k]; }

    // wave-64 inclusive scan of per-thread sums
    float ps = s;
#pragma unroll
    for (int off = 1; off < 64; off <<= 1) {
        float n = __shfl_up(ps, off, 64);
        if ((tid & 63) >= off) ps += n;
    }
    __shared__ float wsum[4];
    if ((tid & 63) == 63) wsum[tid >> 6] = ps;
    __syncthreads();
    float base = 0.f;
#pragma unroll
    for (int wv = 0; wv < 4; ++wv) if (wv < (tid >> 6)) base += wsum[wv];
    float total = wsum[0] + wsum[1] + wsum[2] + wsum[3];   // cum[T-1]
    float cum0  = sc[0];
    float scale = (float)(zl - 1) / (total - cum0);

    float run = base + ps - s;  // exclusive prefix of this thread's chunk
#pragma unroll
    for (int k = 0; k < 8; ++k) {
        run += v[k];
        norm[b * Tn + tid * 8 + k] = (run - cum0) * scale;
    }

    // score_loss partial: diff_t = score[t]*scale (== norm[t]-norm[t-1] exactly in math)
    float ls = 0.f;
#pragma unroll
    for (int k = 0; k < 8; ++k) {
        int t = tid * 8 + k;
        if (t >= 1 && t < xl) {
            float diff = v[k] * scale;
            ls += fmaxf(diff - 1.0f, 0.f);
        }
    }
#pragma unroll
    for (int off = 32; off; off >>= 1) ls += __shfl_down(ls, off, 64);
    __shared__ float lw[4];
    if ((tid & 63) == 0) lw[tid >> 6] = ls;
    __syncthreads();
    if (tid == 0) loss_part[b] = (lw[0] + lw[1] + lw[2] + lw[3]) / (float)(xl - 1);

    for (int l = tid; l < Ln; l += 256)
        zmask_out[b * Ln + l] = (l * 4 < xl) ? 1.f : 0.f;
    if (tid == 0) zlen_out[b] = (float)zl;
}

// ---------------- K2b: mean of loss partials ----------------------------
__global__ void loss_kernel(const float* __restrict__ loss_part, float* __restrict__ out_loss) {
    if (threadIdx.x == 0) {
        float s = 0.f;
        for (int i = 0; i < Bn; ++i) s += loss_part[i];
        out_loss[0] = s / (float)Bn;
    }
}

// ---------------- K3: alignment[b,l,:] = softmax_t(-5(l-norm)^2) ---------
__global__ __launch_bounds__(256) void softmax_kernel(const float* __restrict__ norm,
                                                      const int* __restrict__ xlen,
                                                      float* __restrict__ align) {
    int bl  = blockIdx.x;            // b*L + l
    int b   = bl >> 9;
    int l   = bl & (Ln - 1);
    int tid = threadIdx.x;
    int xl  = xlen[b];
    int zl  = (xl + 3) >> 2;
    float* arow = align + (size_t)bl * Tn;
    if (l >= zl) {
#pragma unroll
        for (int k = 0; k < 8; ++k) arow[tid + k * 256] = 0.f;
        return;
    }
    const float* nb = norm + b * Tn;
    float dv[8], mx = -1e30f;
#pragma unroll
    for (int k = 0; k < 8; ++k) {
        int t = tid + k * 256;
        float df = (float)l - nb[t];
        float dd = -kSigmaSq * df * df;
        dv[k] = (t < xl) ? dd : -1e30f;
        mx = fmaxf(mx, dv[k]);
    }
#pragma unroll
    for (int off = 32; off; off >>= 1) mx = fmaxf(mx, __shfl_xor(mx, off, 64));
    __shared__ float sr1[4], sr2[4];
    if ((tid & 63) == 0) sr1[tid >> 6] = mx;
    __syncthreads();
    mx = fmaxf(fmaxf(sr1[0], sr1[1]), fmaxf(sr1[2], sr1[3]));
    float e[8], sum = 0.f;
#pragma unroll
    for (int k = 0; k < 8; ++k) { e[k] = __expf(dv[k] - mx); sum += e[k]; }
#pragma unroll
    for (int off = 32; off; off >>= 1) sum += __shfl_xor(sum, off, 64);
    if ((tid & 63) == 0) sr2[tid >> 6] = sum;
    __syncthreads();
    sum = sr2[0] + sr2[1] + sr2[2] + sr2[3];
    float inv = 1.0f / sum;
#pragma unroll
    for (int k = 0; k < 8; ++k) arow[tid + k * 256] = e[k] * inv;
}

// ---------------- K4: z[b,d,l] = sum_t align[b,l,t]*x[b,d,t] (windowed) --
__device__ __forceinline__ int lb_ge(const float* a, int n, float v) {
    int lo = 0, hi = n;
    while (lo < hi) { int m = (lo + hi) >> 1; if (a[m] < v) lo = m + 1; else hi = m; }
    return lo;
}
__device__ __forceinline__ int ub_gt(const float* a, int n, float v) {
    int lo = 0, hi = n;
    while (lo < hi) { int m = (lo + hi) >> 1; if (a[m] <= v) lo = m + 1; else hi = m; }
    return lo;
}

#define LT 32
#define DT 64
#define TC 32

__global__ __launch_bounds__(256) void zgemm_kernel(const float* __restrict__ x,
                                                    const float* __restrict__ align,
                                                    const float* __restrict__ norm,
                                                    const int* __restrict__ xlen,
                                                    float* __restrict__ z) {
    int lt = blockIdx.x & 15;            // 16 l-tiles
    int dt = (blockIdx.x >> 4) & 7;      // 8 d-tiles
    int b  = blockIdx.x >> 7;
    int l0 = lt * LT, d0 = dt * DT;
    int xl = xlen[b];
    const float* nb = norm + b * Tn;

    // contiguous t-window: alignment negligible beyond |l - norm| > 4
    int t_lo = lb_ge(nb, Tn, (float)l0 - 4.0f);
    int t_hi = ub_gt(nb, Tn, (float)(l0 + LT - 1) + 4.0f);
    if (t_hi > xl) t_hi = xl;

    __shared__ float sX[DT][TC + 1];
    __shared__ float sA[LT][TC + 1];

    int tid = threadIdx.x;
    int lg = tid & 15;    // l = l0 + lg*2 + {0,1}
    int dg = tid >> 4;    // d = d0 + dg*4 + {0..3}
    float acc[4][2] = {{0.f,0.f},{0.f,0.f},{0.f,0.f},{0.f,0.f}};

    for (int t0 = t_lo; t0 < t_hi; t0 += TC) {
#pragma unroll
        for (int i = 0; i < 4; ++i) {
            int idx = i * 256 + tid; int r = idx >> 5, c = idx & 31; int t = t0 + c;
            sA[r][c] = (t < t_hi) ? align[((size_t)(b * Ln + l0 + r)) * Tn + t] : 0.f;
        }
#pragma unroll
        for (int i = 0; i < 8; ++i) {
            int idx = i * 256 + tid; int r = idx >> 5, c = idx & 31; int t = t0 + c;
            sX[r][c] = (t < t_hi) ? x[((size_t)(b * Dn + d0 + r)) * Tn + t] : 0.f;
        }
        __syncthreads();
#pragma unroll
        for (int t = 0; t < TC; ++t) {
            float a0 = sA[lg * 2][t], a1 = sA[lg * 2 + 1][t];
            float x0 = sX[dg * 4 + 0][t];
            float x1 = sX[dg * 4 + 1][t];
            float x2 = sX[dg * 4 + 2][t];
            float x3 = sX[dg * 4 + 3][t];
            acc[0][0] = fmaf(x0, a0, acc[0][0]); acc[0][1] = fmaf(x0, a1, acc[0][1]);
            acc[1][0] = fmaf(x1, a0, acc[1][0]); acc[1][1] = fmaf(x1, a1, acc[1][1]);
            acc[2][0] = fmaf(x2, a0, acc[2][0]); acc[2][1] = fmaf(x2, a1, acc[2][1]);
            acc[3][0] = fmaf(x3, a0, acc[3][0]); acc[3][1] = fmaf(x3, a1, acc[3][1]);
        }
        __syncthreads();
    }
#pragma unroll
    for (int jj = 0; jj < 4; ++jj)
#pragma unroll
        for (int ii = 0; ii < 2; ++ii)
            z[((size_t)(b * Dn + d0 + dg * 4 + jj)) * Ln + (l0 + lg * 2 + ii)] = acc[jj][ii];
}

extern "C" void kernel_launch(void* const* d_in, const int* in_sizes, int n_in,
                              void* d_out, int out_size, void* d_ws, size_t ws_size,
                              hipStream_t stream) {
    const float* x    = (const float*)d_in[0];
    const float* w    = (const float*)d_in[1];
    // d_in[2] = x_mask (bool) — derived from x_lengths instead
    const int*   xlen = (const int*)d_in[3];
    float* out = (float*)d_out;

    const size_t OFF_Z     = 0;
    const size_t OFF_ZMASK = (size_t)Bn * Dn * Ln;            // 4194304
    const size_t OFF_ZLEN  = OFF_ZMASK + (size_t)Bn * Ln;     // +8192
    const size_t OFF_ALIGN = OFF_ZLEN + Bn;                   // +16
    const size_t OFF_LOSS  = OFF_ALIGN + (size_t)Bn * Ln * Tn;

    float* score     = (float*)d_ws;
    float* norm      = score + (size_t)Bn * Tn;
    float* loss_part = norm + (size_t)Bn * Tn;

    score_kernel<<<Bn * (Tn / 64), 256, 0, stream>>>(x, w, xlen, score);
    scan_kernel<<<Bn, 256, 0, stream>>>(score, xlen, norm, loss_part,
                                        out + OFF_ZMASK, out + OFF_ZLEN);
    loss_kernel<<<1, 64, 0, stream>>>(loss_part, out + OFF_LOSS);
    softmax_kernel<<<Bn * Ln, 256, 0, stream>>>(norm, xlen, out + OFF_ALIGN);
    zgemm_kernel<<<Bn * 8 * 16, 256, 0, stream>>>(x, out + OFF_ALIGN, norm, xlen,
                                                  out + OFF_Z);
}

// Round 2
// 75.629 us; speedup vs baseline: 1.0625x; 1.0625x over previous
//
#include <hip/hip_runtime.h>
#include <cstddef>

#define Bn 16
#define Dn 512
#define Tn 2048
#define Ln 512

__constant__ float kSigmaSq = 5.0f;

// ---------------- K1: score[b,t] = exp(x[b,:,t].w) * mask ----------------
__global__ __launch_bounds__(256) void score_kernel(const float* __restrict__ x,
                                                    const float* __restrict__ w,
                                                    const int* __restrict__ xlen,
                                                    float* __restrict__ score) {
    int blk  = blockIdx.x;          // B * (T/64) = 512 blocks
    int b    = blk >> 5;
    int tc   = blk & 31;
    int lane = threadIdx.x & 63;
    int dg   = threadIdx.x >> 6;    // 4 d-groups of 128
    int t    = tc * 64 + lane;
    const float* xb = x + (size_t)b * Dn * Tn;
    float acc = 0.f;
    int d0 = dg * 128;
#pragma unroll 8
    for (int d = d0; d < d0 + 128; ++d)
        acc = fmaf(xb[(size_t)d * Tn + t], w[d], acc);
    __shared__ float red[4][64];
    red[dg][lane] = acc;
    __syncthreads();
    if (dg == 0) {
        float s = red[0][lane] + red[1][lane] + red[2][lane] + red[3][lane];
        score[b * Tn + t] = (t < xlen[b]) ? __expf(s) : 0.f;
    }
}

// ---------------- K2: per-b scan -> norm, loss partial, z_mask, z_len ----
__global__ __launch_bounds__(256) void scan_kernel(const float* __restrict__ score,
                                                   const int* __restrict__ xlen,
                                                   float* __restrict__ norm,
                                                   float* __restrict__ loss_part,
                                                   float* __restrict__ zmask_out,
                                                   float* __restrict__ zlen_out) {
    int b = blockIdx.x, tid = threadIdx.x;
    int xl = xlen[b];
    int zl = (xl + 3) >> 2;
    const float* sc = score + b * Tn;

    float v[8]; float s = 0.f;
#pragma unroll
    for (int k = 0; k < 8; ++k) { v[k] = sc[tid * 8 + k]; s += v[k]; }

    // wave-64 inclusive scan of per-thread sums
    float ps = s;
#pragma unroll
    for (int off = 1; off < 64; off <<= 1) {
        float n = __shfl_up(ps, off, 64);
        if ((tid & 63) >= off) ps += n;
    }
    __shared__ float wsum[4];
    if ((tid & 63) == 63) wsum[tid >> 6] = ps;
    __syncthreads();
    float base = 0.f;
#pragma unroll
    for (int wv = 0; wv < 4; ++wv) if (wv < (tid >> 6)) base += wsum[wv];
    float total = wsum[0] + wsum[1] + wsum[2] + wsum[3];   // cum[T-1]
    float cum0  = sc[0];
    float scale = (float)(zl - 1) / (total - cum0);

    float run = base + ps - s;  // exclusive prefix of this thread's chunk
#pragma unroll
    for (int k = 0; k < 8; ++k) {
        run += v[k];
        norm[b * Tn + tid * 8 + k] = (run - cum0) * scale;
    }

    // score_loss partial: diff_t = score[t]*scale
    float ls = 0.f;
#pragma unroll
    for (int k = 0; k < 8; ++k) {
        int t = tid * 8 + k;
        if (t >= 1 && t < xl) {
            float diff = v[k] * scale;
            ls += fmaxf(diff - 1.0f, 0.f);
        }
    }
#pragma unroll
    for (int off = 32; off; off >>= 1) ls += __shfl_down(ls, off, 64);
    __shared__ float lw[4];
    if ((tid & 63) == 0) lw[tid >> 6] = ls;
    __syncthreads();
    if (tid == 0) loss_part[b] = (lw[0] + lw[1] + lw[2] + lw[3]) / (float)(xl - 1);

    for (int l = tid; l < Ln; l += 256)
        zmask_out[b * Ln + l] = (l * 4 < xl) ? 1.f : 0.f;
    if (tid == 0) zlen_out[b] = (float)zl;
}

// ---------------- K2b: mean of loss partials ----------------------------
__global__ void loss_kernel(const float* __restrict__ loss_part, float* __restrict__ out_loss) {
    if (threadIdx.x == 0) {
        float s = 0.f;
        for (int i = 0; i < Bn; ++i) s += loss_part[i];
        out_loss[0] = s / (float)Bn;
    }
}

// ---------------- K3: alignment[b,l,:] = softmax_t(-5(l-norm)^2) ---------
__global__ __launch_bounds__(256) void softmax_kernel(const float* __restrict__ norm,
                                                      const int* __restrict__ xlen,
                                                      float* __restrict__ align) {
    int bl  = blockIdx.x;            // b*L + l
    int b   = bl >> 9;
    int l   = bl & (Ln - 1);
    int tid = threadIdx.x;
    int xl  = xlen[b];
    int zl  = (xl + 3) >> 2;
    float* arow = align + (size_t)bl * Tn;
    if (l >= zl) {
#pragma unroll
        for (int k = 0; k < 8; ++k) arow[tid + k * 256] = 0.f;
        return;
    }
    const float* nb = norm + b * Tn;
    float dv[8], mx = -1e30f;
#pragma unroll
    for (int k = 0; k < 8; ++k) {
        int t = tid + k * 256;
        float df = (float)l - nb[t];
        float dd = -kSigmaSq * df * df;
        dv[k] = (t < xl) ? dd : -1e30f;
        mx = fmaxf(mx, dv[k]);
    }
#pragma unroll
    for (int off = 32; off; off >>= 1) mx = fmaxf(mx, __shfl_xor(mx, off, 64));
    __shared__ float sr1[4], sr2[4];
    if ((tid & 63) == 0) sr1[tid >> 6] = mx;
    __syncthreads();
    mx = fmaxf(fmaxf(sr1[0], sr1[1]), fmaxf(sr1[2], sr1[3]));
    float e[8], sum = 0.f;
#pragma unroll
    for (int k = 0; k < 8; ++k) { e[k] = __expf(dv[k] - mx); sum += e[k]; }
#pragma unroll
    for (int off = 32; off; off >>= 1) sum += __shfl_xor(sum, off, 64);
    if ((tid & 63) == 0) sr2[tid >> 6] = sum;
    __syncthreads();
    sum = sr2[0] + sr2[1] + sr2[2] + sr2[3];
    float inv = 1.0f / sum;
#pragma unroll
    for (int k = 0; k < 8; ++k) arow[tid + k * 256] = e[k] * inv;
}

// ---------------- K4: z[b,d,l] = sum_t align[b,l,t]*x[b,d,t] (windowed) --
__device__ __forceinline__ int lb_ge(const float* a, int n, float v) {
    int lo = 0, hi = n;
    while (lo < hi) { int m = (lo + hi) >> 1; if (a[m] < v) lo = m + 1; else hi = m; }
    return lo;
}
__device__ __forceinline__ int ub_gt(const float* a, int n, float v) {
    int lo = 0, hi = n;
    while (lo < hi) { int m = (lo + hi) >> 1; if (a[m] <= v) lo = m + 1; else hi = m; }
    return lo;
}

// Block tile: 256 d x 32 l, TC=32 t-chunk. 256 threads, per-thread 8d x 4l.
// LDS t-major, sX cols XOR-swizzled (r ^ 8*(t>>2 & 7)) -> dense b128 reads,
// <=2-way staging writes. Double-buffered; loads issued early, ds_write late.
__global__ __launch_bounds__(256) void zgemm2_kernel(const float* __restrict__ x,
                                                     const float* __restrict__ align,
                                                     const float* __restrict__ norm,
                                                     const int* __restrict__ xlen,
                                                     float* __restrict__ z) {
    int lt = blockIdx.x & 15;            // 16 l-tiles
    int dh = (blockIdx.x >> 4) & 1;      // 2 d-halves of 256
    int b  = blockIdx.x >> 5;
    int l0 = lt * 32, d0 = dh * 256;
    int xl = xlen[b];
    const float* nb = norm + b * Tn;

    int t_lo = lb_ge(nb, Tn, (float)l0 - 4.0f) & ~31;          // 32-aligned down
    int t_hi = ub_gt(nb, Tn, (float)(l0 + 31) + 4.0f);
    if (t_hi > xl) t_hi = xl;
    int ntiles = (t_hi > t_lo) ? ((t_hi - t_lo + 31) >> 5) : 0;

    __shared__ float sX[2][32][256];
    __shared__ float sA[2][32][36];      // +4 pad: 16B-aligned rows, spread banks

    int tid = threadIdx.x;
    int dg  = tid & 31;                  // 32 groups * 8 d
    int lg  = tid >> 5;                  // 8 groups * 4 l
    int rr  = tid >> 3, cc = tid & 7;    // staging: row group / float4 along t

    float acc[8][4] = {};
    float4 rx[8]; float4 ra;

    const float* xb = x + ((size_t)(b * Dn + d0)) * Tn;
    const float* ab = align + ((size_t)(b * Ln + l0)) * Tn;

#define STAGE_LOAD(T0)                                                        \
    {                                                                         \
        _Pragma("unroll")                                                     \
        for (int i = 0; i < 8; ++i)                                           \
            rx[i] = *(const float4*)&xb[(size_t)(i * 32 + rr) * Tn + (T0) + cc * 4]; \
        ra = *(const float4*)&ab[(size_t)rr * Tn + (T0) + cc * 4];            \
    }
#define STAGE_WRITE(BUF)                                                      \
    {                                                                         \
        _Pragma("unroll")                                                     \
        for (int i = 0; i < 8; ++i) {                                         \
            int r = i * 32 + rr;                                              \
            int col = r ^ (cc << 3);                                          \
            sX[BUF][cc * 4 + 0][col] = rx[i].x;                               \
            sX[BUF][cc * 4 + 1][col] = rx[i].y;                               \
            sX[BUF][cc * 4 + 2][col] = rx[i].z;                               \
            sX[BUF][cc * 4 + 3][col] = rx[i].w;                               \
        }                                                                     \
        sA[BUF][cc * 4 + 0][rr] = ra.x;                                       \
        sA[BUF][cc * 4 + 1][rr] = ra.y;                                       \
        sA[BUF][cc * 4 + 2][rr] = ra.z;                                       \
        sA[BUF][cc * 4 + 3][rr] = ra.w;                                       \
    }

    if (ntiles > 0) { STAGE_LOAD(t_lo); STAGE_WRITE(0); }
    __syncthreads();

    for (int it = 0; it < ntiles; ++it) {
        int buf = it & 1;
        if (it + 1 < ntiles) STAGE_LOAD(t_lo + (it + 1) * 32);
#pragma unroll
        for (int t = 0; t < 32; ++t) {
            int s8 = (t >> 2) << 3;
            const float4 xa = *(const float4*)&sX[buf][t][(4 * dg) ^ s8];
            const float4 xc = *(const float4*)&sX[buf][t][(128 + 4 * dg) ^ s8];
            const float4 av = *(const float4*)&sA[buf][t][4 * lg];
            float xv[8] = {xa.x, xa.y, xa.z, xa.w, xc.x, xc.y, xc.z, xc.w};
            float aw[4] = {av.x, av.y, av.z, av.w};
#pragma unroll
            for (int i = 0; i < 8; ++i)
#pragma unroll
                for (int j = 0; j < 4; ++j)
                    acc[i][j] = fmaf(xv[i], aw[j], acc[i][j]);
        }
        if (it + 1 < ntiles) STAGE_WRITE(buf ^ 1);
        __syncthreads();
    }

    // write out: thread owns d in {d0+4dg..+3, d0+128+4dg..+3}, l = l0+4lg..+3
#pragma unroll
    for (int i = 0; i < 8; ++i) {
        int d = d0 + (i < 4 ? 4 * dg + i : 128 + 4 * dg + (i - 4));
        float4 v = make_float4(acc[i][0], acc[i][1], acc[i][2], acc[i][3]);
        *(float4*)&z[((size_t)(b * Dn + d)) * Ln + l0 + 4 * lg] = v;
    }
#undef STAGE_LOAD
#undef STAGE_WRITE
}

extern "C" void kernel_launch(void* const* d_in, const int* in_sizes, int n_in,
                              void* d_out, int out_size, void* d_ws, size_t ws_size,
                              hipStream_t stream) {
    const float* x    = (const float*)d_in[0];
    const float* w    = (const float*)d_in[1];
    const int*   xlen = (const int*)d_in[3];
    float* out = (float*)d_out;

    const size_t OFF_Z     = 0;
    const size_t OFF_ZMASK = (size_t)Bn * Dn * Ln;            // 4194304
    const size_t OFF_ZLEN  = OFF_ZMASK + (size_t)Bn * Ln;     // +8192
    const size_t OFF_ALIGN = OFF_ZLEN + Bn;                   // +16
    const size_t OFF_LOSS  = OFF_ALIGN + (size_t)Bn * Ln * Tn;

    float* score     = (float*)d_ws;
    float* norm      = score + (size_t)Bn * Tn;
    float* loss_part = norm + (size_t)Bn * Tn;

    score_kernel<<<Bn * (Tn / 64), 256, 0, stream>>>(x, w, xlen, score);
    scan_kernel<<<Bn, 256, 0, stream>>>(score, xlen, norm, loss_part,
                                        out + OFF_ZMASK, out + OFF_ZLEN);
    loss_kernel<<<1, 64, 0, stream>>>(loss_part, out + OFF_LOSS);
    softmax_kernel<<<Bn * Ln, 256, 0, stream>>>(norm, xlen, out + OFF_ALIGN);
    zgemm2_kernel<<<Bn * 2 * 16, 256, 0, stream>>>(x, out + OFF_ALIGN, norm, xlen,
                                                   out + OFF_Z);
}